// Round 5
// baseline (210.356 us; speedup 1.0000x reference)
//
#include <hip/hip_runtime.h>
#include <hip/hip_bf16.h>

#define NGRAPH 16
#define NNODE 1024
#define DDIM 64

typedef __attribute__((ext_vector_type(8))) short bf16x8;
typedef __attribute__((ext_vector_type(4))) float f32x4;

// ---- workspace layout (float offsets) ----
#define OFF_ROWSUM 0            // 16384
#define OFF_DIAG   16384        // 16384
#define OFF_P1     32768        // 16384
#define OFF_R      49152        // 16384
#define OFF_CS     65536        // 16*8*64 = 8192
#define OFF_S      73728        // 16 (+ pad)
#define OFF_S2P    75840        // 16384
#define OFF_R2P    92224        // 16384
#define OFF_BASE0  110656       // 16*1024*64 = 1048576
#define OFF_X2T    1159232      // ushort area: 16*64*1024 ushorts = 524288 floats

__device__ __forceinline__ unsigned short f2bf(float f) {
    unsigned int u = __float_as_uint(f);
    u = (u + 0x7fffu + ((u >> 16) & 1u)) >> 16;
    return (unsigned short)u;
}

// single-instruction packed f32->bf16 (RNE, same rounding as f2bf)
__device__ __forceinline__ unsigned int cvt_pk_bf16(float lo, float hi) {
    unsigned int r;
    asm("v_cvt_pk_bf16_f32 %0, %1, %2" : "=v"(r) : "v"(lo), "v"(hi));
    return r;
}

__device__ __forceinline__ float wave_reduce(float v) {
    #pragma unroll
    for (int off = 32; off; off >>= 1) v += __shfl_down(v, off, 64);
    return v;
}

// ---------------- kA: A row sums + diag  |  X column sums + p1 = X @ wA1 ----------------
__global__ __launch_bounds__(256) void kA_stats(const float* __restrict__ A,
                                                const float* __restrict__ X,
                                                const float* __restrict__ wA1,
                                                float* __restrict__ rowsum,
                                                float* __restrict__ diagv,
                                                float* __restrict__ p1,
                                                float* __restrict__ colsum_part) {
    if (blockIdx.x < NGRAPH * NNODE / 4) {
        int row  = blockIdx.x * 4 + (threadIdx.x >> 6);
        int lane = threadIdx.x & 63;
        const float4* b4 = (const float4*)(A + (size_t)row * NNODE);
        float sum = 0.f;
        #pragma unroll
        for (int it = 0; it < 4; ++it) {
            float4 v = b4[lane + it * 64];
            sum += v.x + v.y + v.z + v.w;
        }
        sum = wave_reduce(sum);
        if (lane == 0) {
            rowsum[row] = sum;
            int i = row & (NNODE - 1);
            diagv[row] = ((const float*)b4)[i];
        }
    } else {
        int bid  = blockIdx.x - NGRAPH * NNODE / 4;
        int b    = bid >> 3;
        int blk  = bid & 7;
        int wv   = threadIdx.x >> 6;
        int lane = threadIdx.x & 63;
        float w = wA1[lane];
        float cs = 0.f;
        int row0 = blk * 128 + wv * 32;
        const float* Xb = X + (size_t)b * NNODE * DDIM;
        for (int rI = 0; rI < 32; ++rI) {
            int i = row0 + rI;
            float x = Xb[i * DDIM + lane];
            cs += x;
            float v = wave_reduce(x * w);
            if (lane == 0) p1[b * NNODE + i] = v;
        }
        __shared__ float csl[4][64];
        csl[wv][lane] = cs;
        __syncthreads();
        if (threadIdx.x < 64) {
            float t = csl[0][lane] + csl[1][lane] + csl[2][lane] + csl[3][lane];
            colsum_part[(b * 8 + blk) * 64 + lane] = t;
        }
    }
}

// ---------------- kB: per-graph stats (recomputed per block) + per-node transforms ----------------
__global__ __launch_bounds__(256) void kB_nodes(const float* __restrict__ X,
                                                const float* __restrict__ coeffs,
                                                const float* __restrict__ wA2,
                                                const float* __restrict__ w11,
                                                const float* __restrict__ w12,
                                                const float* __restrict__ w13,
                                                const float* __restrict__ w14,
                                                const float* __restrict__ w15,
                                                const float* __restrict__ w16,
                                                const float* __restrict__ w21,
                                                const float* __restrict__ w22,
                                                const float* __restrict__ w23,
                                                const float* __restrict__ w24,
                                                const float* __restrict__ w25,
                                                const float* __restrict__ w26,
                                                const float* __restrict__ rowsum,
                                                const float* __restrict__ diagv,
                                                const float* __restrict__ colsum_part,
                                                const float* __restrict__ p1g,
                                                float* __restrict__ rws,
                                                float* __restrict__ base0,
                                                unsigned short* __restrict__ x2tg,
                                                float* __restrict__ S2part,
                                                float* __restrict__ R2part,
                                                float* __restrict__ sArr) {
    __shared__ float Xl[64][68];
    __shared__ float w1l[64][68];
    __shared__ float w2l[64][68];
    __shared__ unsigned short X2Tl[64][68];
    __shared__ float rm_l[64], dg_l[64], r_l[64];
    __shared__ float redS[4][64], redR[4][64];
    __shared__ float redA[4], redD[4];
    __shared__ float mxs[64], p2s;
    __shared__ float pg1_l[64], pg2_l[64];

    int b    = blockIdx.x >> 4;
    int tile = blockIdx.x & 15;
    int i0   = tile * 64;
    int tid  = threadIdx.x;
    int e    = tid & 63;
    int wv   = tid >> 6;

    // --- stage X tile + weights ---
    const float* Xg = X + (size_t)b * (NNODE * DDIM) + (size_t)i0 * DDIM;
    #pragma unroll
    for (int it = 0; it < 4; ++it) {
        int g   = it * 256 + tid;
        int row = g >> 4;
        int c4  = (g & 15) << 2;
        float4 v  = ((const float4*)Xg)[g];
        *(float4*)&Xl[row][c4] = v;
        float4 v1 = ((const float4*)w11)[g];
        *(float4*)&w1l[row][c4] = v1;
        float4 v2 = ((const float4*)w21)[g];
        *(float4*)&w2l[row][c4] = v2;
    }

    // --- per-graph scalar stats (every block recomputes; cheap) ---
    float sa = 0.f, sd = 0.f;
    for (int i = tid; i < NNODE; i += 256) {
        sa += rowsum[b * NNODE + i];
        sd += diagv[b * NNODE + i];
    }
    sa = wave_reduce(sa); sd = wave_reduce(sd);
    if (e == 0) { redA[wv] = sa; redD[wv] = sd; }
    if (tid < 64) {
        float mx = 0.f;
        for (int k = 0; k < 8; ++k) mx += colsum_part[(b * 8 + k) * 64 + tid];
        mxs[tid] = mx * (1.f / (float)NNODE);
    }
    __syncthreads();
    float mean_all  = (redA[0] + redA[1] + redA[2] + redA[3]) * (1.f / ((float)NNODE * (float)NNODE));
    float mean_diag = (redD[0] + redD[1] + redD[2] + redD[3]) * (1.f / (float)NNODE);
    float c3 = coeffs[3], c4c = coeffs[4];

    // --- per-graph vectors: one wave per section (concurrent, not serial) ---
    if (wv == 0) {
        float a1 = 0.f;
        for (int d = 0; d < 64; ++d) a1 += mxs[d] * w12[e * 64 + d];
        pg1_l[e] = a1 + mean_diag * w15[e] + mean_all * w16[e];
    } else if (wv == 1) {
        float a2 = 0.f;
        for (int d = 0; d < 64; ++d) a2 += mxs[d] * w22[e * 64 + d];
        pg2_l[e] = a2 + mean_diag * w25[e] + mean_all * w26[e];
    } else if (wv == 2) {
        float v = wave_reduce(mxs[e] * wA2[e]);
        if (e == 0) p2s = v;
    } else {
        float rs  = rowsum[b * NNODE + i0 + e];
        float dgv = diagv[b * NNODE + i0 + e];
        float rmv = rs * (1.f / (float)NNODE);
        rm_l[e] = rmv;
        dg_l[e] = dgv;
        float rv = c3 * rmv + c4c * dgv + p1g[b * NNODE + i0 + e];
        r_l[e] = rv;
        rws[b * NNODE + i0 + e] = rv;
    }
    __syncthreads();
    if (tile == 0 && tid == 0)
        sArr[b] = coeffs[1] * mean_all + coeffs[2] * mean_diag + p2s;

    float w13e = w13[e], w14e = w14[e], w23e = w23[e], w24e = w24[e];
    float pg1e = pg1_l[e], pg2e = pg2_l[e];

    float acc1[16], acc2[16];
    #pragma unroll
    for (int t = 0; t < 16; ++t) { acc1[t] = 0.f; acc2[t] = 0.f; }

    for (int d0 = 0; d0 < 64; d0 += 4) {
        float4 w1v = *(const float4*)&w1l[e][d0];
        float4 w2v = *(const float4*)&w2l[e][d0];
        #pragma unroll
        for (int t = 0; t < 16; ++t) {
            int li = wv + 4 * t;
            float4 xv = *(const float4*)&Xl[li][d0];
            acc1[t] += xv.x * w1v.x + xv.y * w1v.y + xv.z * w1v.z + xv.w * w1v.w;
            acc2[t] += xv.x * w2v.x + xv.y * w2v.y + xv.z * w2v.z + xv.w * w2v.w;
        }
    }

    float s2acc = 0.f, r2acc = 0.f;
    #pragma unroll
    for (int t = 0; t < 16; ++t) {
        int li = wv + 4 * t;
        int i  = i0 + li;
        float rmv = rm_l[li], dgv = dg_l[li];
        float x2t = acc2[t] + rmv * w23e + dgv * w24e + pg2e;
        float b0  = acc1[t] + rmv * w13e + dgv * w14e + pg1e;
        base0[((size_t)(b * NNODE + i)) * 64 + e] = b0;
        X2Tl[e][li] = f2bf(x2t);
        s2acc += x2t;
        r2acc += r_l[li] * x2t;
    }
    redS[wv][e] = s2acc;
    redR[wv][e] = r2acc;
    __syncthreads();

    for (int k = 0; k < 16; ++k) {
        int ep = wv * 16 + k;
        unsigned short v = X2Tl[ep][e];
        x2tg[((size_t)(b * 64 + ep)) * NNODE + i0 + e] = v;
    }
    if (tid < 64) {
        float s2 = redS[0][tid] + redS[1][tid] + redS[2][tid] + redS[3][tid];
        float r2 = redR[0][tid] + redR[1][tid] + redR[2][tid] + redR[3][tid];
        S2part[(b * 16 + tile) * 64 + tid] = s2;
        R2part[(b * 16 + tile) * 64 + tid] = r2;
    }
}

// ---------------- kC: fused A_t + bf16 MFMA c0*(A @ X2t) + epilogue ----------------
// R5: K-SPLIT x2 for occupancy (resubmitted after infra failure).
//  - Each 16-row tile is processed by TWO waves: wave h owns kt in {4h..4h+3}.
//    Disjoint A loads / A_t stores / B loads (zero traffic change); partial
//    accumulators combined via an LDS exchange at the end.
//  - Grid 512 blocks (2 tiles/block) -> 8 waves/CU (was 4): memory-pipe gaps
//    during one wave's VALU/MFMA phases get filled by the co-resident waves.
//  - A loaded directly in MFMA fragment layout (16 rows x 128B segments);
//    1-kt-ahead A prefetch; cvt_pk_bf16 in-register pack; normal stores
//    (round-1 lesson: L2 write-back merges the 16B/32B-stride partials).
__global__ __launch_bounds__(256, 2) void kC_main(const float* __restrict__ A,
                                               const float* __restrict__ coeffs,
                                               const float* __restrict__ sArr,
                                               const float* __restrict__ rArr,
                                               const unsigned short* __restrict__ x2tg,
                                               const float* __restrict__ base0,
                                               const float* __restrict__ S2part,
                                               const float* __restrict__ R2part,
                                               float* __restrict__ At,
                                               float* __restrict__ outp) {
    __shared__ float r_lds[1024];
    __shared__ float s2_lds[64], r2_lds[64];
    __shared__ float accx[2][2][64][8];   // [tile-in-block][writer-half][lane][2 slices x f32x4]

    int b    = blockIdx.x >> 5;      // 32 blocks per graph
    int tb   = blockIdx.x & 31;
    int tid  = threadIdx.x;
    int lane = tid & 63, wv = tid >> 6;
    int tIdx = wv >> 1;              // tile within block: 0..1
    int h    = wv & 1;               // K-half: kt in {4h..4h+3}
    int tile = tb * 2 + tIdx;        // 0..63
    int i0   = tile * 16;
    int m    = lane & 15, q = lane >> 4;

    // stage r (1024 floats); threads<64 also reduce S2/R2 partials
    float4 rv = ((const float4*)(rArr + b * NNODE))[tid];
    *(float4*)&r_lds[tid * 4] = rv;
    if (tid < 64) {
        float s2 = 0.f, r2 = 0.f;
        #pragma unroll
        for (int t = 0; t < 16; ++t) {
            s2 += S2part[(b * 16 + t) * 64 + tid];
            r2 += R2part[(b * 16 + t) * 64 + tid];
        }
        s2_lds[tid] = s2 * (1.f / (float)NNODE);
        r2_lds[tid] = r2 * (1.f / (float)NNODE);
    }

    float sb  = sArr[b];
    float c0  = coeffs[0];
    float c0n = c0 * (1.f / (float)NNODE);

    // per-lane fragment-layout pointers
    const float* Aw  = A  + ((size_t)(b * NNODE + i0 + m)) * NNODE + q * 8;
    float*       Atw = At + ((size_t)(b * NNODE + i0 + m)) * NNODE + q * 8;
    const unsigned short* Bw = x2tg + ((size_t)(b * 64 + m)) * NNODE + q * 8;

    int kt0 = 4 * h;

    // prefetch first kt's A fragment (no LDS dependency -> issue before the barrier)
    f32x4 a[8], an[8];
    #pragma unroll
    for (int ks = 0; ks < 4; ++ks) {
        a[2 * ks]     = *(const f32x4*)(Aw + kt0 * 128 + ks * 32);
        a[2 * ks + 1] = *(const f32x4*)(Aw + kt0 * 128 + ks * 32 + 4);
    }

    f32x4 acc[4];
    #pragma unroll
    for (int s = 0; s < 4; ++s) acc[s] = (f32x4){0.f, 0.f, 0.f, 0.f};

    __syncthreads();   // r_lds / s2_lds ready; waves independent until the combine

    float bse = sb + r_lds[i0 + m];

    #pragma unroll
    for (int j = 0; j < 4; ++j) {
        int kt = kt0 + j;

        // ---- B fragments for this kt: all 4 output-col slices (L2-resident) ----
        bf16x8 Bf[4][4];
        #pragma unroll
        for (int s = 0; s < 4; ++s) {
            #pragma unroll
            for (int ks = 0; ks < 4; ++ks) {
                Bf[s][ks] = *(const bf16x8*)(Bw + (size_t)s * 16 * NNODE + kt * 128 + ks * 32);
            }
        }

        // ---- prefetch next kt's A fragment (lands during this kt's compute) ----
        if (j < 3) {
            #pragma unroll
            for (int ks = 0; ks < 4; ++ks) {
                an[2 * ks]     = *(const f32x4*)(Aw + (kt + 1) * 128 + ks * 32);
                an[2 * ks + 1] = *(const f32x4*)(Aw + (kt + 1) * 128 + ks * 32 + 4);
            }
        }

        // ---- A_t compute + store (fire-and-forget) + in-register bf16 pack ----
        bf16x8 pka[4];
        #pragma unroll
        for (int ks = 0; ks < 4; ++ks) {
            int cb = kt * 128 + ks * 32 + q * 8;
            f32x4 rj0 = *(const f32x4*)&r_lds[cb];       // wave-broadcast reads
            f32x4 rj1 = *(const f32x4*)&r_lds[cb + 4];
            f32x4 ac0 = a[2 * ks], ac1 = a[2 * ks + 1];
            f32x4 t0, t1;
            t0.x = fmaf(c0, ac0.x, bse + rj0.x);
            t0.y = fmaf(c0, ac0.y, bse + rj0.y);
            t0.z = fmaf(c0, ac0.z, bse + rj0.z);
            t0.w = fmaf(c0, ac0.w, bse + rj0.w);
            t1.x = fmaf(c0, ac1.x, bse + rj1.x);
            t1.y = fmaf(c0, ac1.y, bse + rj1.y);
            t1.z = fmaf(c0, ac1.z, bse + rj1.z);
            t1.w = fmaf(c0, ac1.w, bse + rj1.w);
            *(f32x4*)(Atw + kt * 128 + ks * 32)     = t0;
            *(f32x4*)(Atw + kt * 128 + ks * 32 + 4) = t1;

            union { uint4 u; bf16x8 hh; } cv;
            cv.u.x = cvt_pk_bf16(ac0.x, ac0.y);
            cv.u.y = cvt_pk_bf16(ac0.z, ac0.w);
            cv.u.z = cvt_pk_bf16(ac1.x, ac1.y);
            cv.u.w = cvt_pk_bf16(ac1.z, ac1.w);
            pka[ks] = cv.hh;
        }

        // ---- 16 MFMAs: 4 output-col slices x 4 K-steps of 32 ----
        #pragma unroll
        for (int s = 0; s < 4; ++s) {
            #pragma unroll
            for (int ks = 0; ks < 4; ++ks) {
                acc[s] = __builtin_amdgcn_mfma_f32_16x16x32_bf16(pka[ks], Bf[s][ks], acc[s], 0, 0, 0);
            }
        }

        if (j < 3) {
            #pragma unroll
            for (int u = 0; u < 8; ++u) a[u] = an[u];
        }
    }

    // ---- combine the two K-halves: each wave writes the 2 slices it does NOT
    //      output (its partner's output slices), reads the partner's partials ----
    #pragma unroll
    for (int j = 0; j < 2; ++j) {
        int s = 2 * (1 - h) + j;
        *(f32x4*)&accx[tIdx][h][lane][4 * j] = acc[s];
    }
    __syncthreads();

    // ---- epilogue (2 slices per wave): out = c0/n*(A@X2t) + base0 + (s+r_i)*S2/n + R2/n ----
    #pragma unroll
    for (int j = 0; j < 2; ++j) {
        int s = 2 * h + j;
        f32x4 part = *(const f32x4*)&accx[tIdx][1 - h][lane][4 * j];
        float s2 = s2_lds[s * 16 + m];
        float r2 = r2_lds[s * 16 + m];
        #pragma unroll
        for (int reg = 0; reg < 4; ++reg) {
            int i = i0 + q * 4 + reg;
            float v = (acc[s][reg] + part[reg]) * c0n
                    + base0[((size_t)(b * NNODE + i)) * 64 + s * 16 + m]
                    + (sb + r_lds[i]) * s2 + r2;
            outp[((size_t)(b * NNODE + i)) * 64 + s * 16 + m] = v;
        }
    }
}

extern "C" void kernel_launch(void* const* d_in, const int* in_sizes, int n_in,
                              void* d_out, int out_size, void* d_ws, size_t ws_size,
                              hipStream_t stream) {
    const float* A      = (const float*)d_in[0];
    const float* X      = (const float*)d_in[1];
    const float* coeffs = (const float*)d_in[2];
    const float* wA1    = (const float*)d_in[3];
    const float* wA2    = (const float*)d_in[4];
    const float* w11    = (const float*)d_in[5];
    const float* w12    = (const float*)d_in[6];
    const float* w13    = (const float*)d_in[7];
    const float* w14    = (const float*)d_in[8];
    const float* w15    = (const float*)d_in[9];
    const float* w16    = (const float*)d_in[10];
    const float* w21    = (const float*)d_in[11];
    const float* w22    = (const float*)d_in[12];
    const float* w23    = (const float*)d_in[13];
    const float* w24    = (const float*)d_in[14];
    const float* w25    = (const float*)d_in[15];
    const float* w26    = (const float*)d_in[16];

    float* ws  = (float*)d_ws;
    float* At  = (float*)d_out;
    float* out = (float*)d_out + (size_t)NGRAPH * NNODE * NNODE;

    float* rowsum = ws + OFF_ROWSUM;
    float* diagv  = ws + OFF_DIAG;
    float* p1     = ws + OFF_P1;
    float* rws    = ws + OFF_R;
    float* cspart = ws + OFF_CS;
    float* sArr   = ws + OFF_S;
    float* S2part = ws + OFF_S2P;
    float* R2part = ws + OFF_R2P;
    float* base0  = ws + OFF_BASE0;
    unsigned short* x2tg = (unsigned short*)(ws + OFF_X2T);

    kA_stats<<<NGRAPH * NNODE / 4 + NGRAPH * 8, 256, 0, stream>>>(
        A, X, wA1, rowsum, diagv, p1, cspart);
    kB_nodes<<<NGRAPH * 16, 256, 0, stream>>>(
        X, coeffs, wA2, w11, w12, w13, w14, w15, w16,
        w21, w22, w23, w24, w25, w26,
        rowsum, diagv, cspart, p1,
        rws, base0, x2tg, S2part, R2part, sArr);
    kC_main<<<NGRAPH * 32, 256, 0, stream>>>(
        A, coeffs, sArr, rws, x2tg, base0, S2part, R2part, At, out);
}

// Round 7
// 197.846 us; speedup vs baseline: 1.0632x; 1.0632x over previous
//
#include <hip/hip_runtime.h>
#include <hip/hip_bf16.h>

#define NGRAPH 16
#define NNODE 1024
#define DDIM 64

typedef __attribute__((ext_vector_type(8))) short bf16x8;
typedef __attribute__((ext_vector_type(4))) float f32x4;

// ---- workspace layout (float offsets) ----
#define OFF_ROWSUM 0            // 16384
#define OFF_DIAG   16384        // 16384
#define OFF_P1     32768        // 16384
#define OFF_R      49152        // 16384
#define OFF_CS     65536        // 16*8*64 = 8192
#define OFF_S      73728        // 16 (+ pad)
#define OFF_S2P    75840        // 16384
#define OFF_R2P    92224        // 16384
#define OFF_BASE0  110656       // 16*1024*64 = 1048576
#define OFF_X2T    1159232      // ushort area: 16*8*64*128 ushorts = 524288 floats

__device__ __forceinline__ unsigned short f2bf(float f) {
    unsigned int u = __float_as_uint(f);
    u = (u + 0x7fffu + ((u >> 16) & 1u)) >> 16;
    return (unsigned short)u;
}

// single-instruction packed f32->bf16 (RNE, same rounding as f2bf)
__device__ __forceinline__ unsigned int cvt_pk_bf16(float lo, float hi) {
    unsigned int r;
    asm("v_cvt_pk_bf16_f32 %0, %1, %2" : "=v"(r) : "v"(lo), "v"(hi));
    return r;
}

__device__ __forceinline__ float wave_reduce(float v) {
    #pragma unroll
    for (int off = 32; off; off >>= 1) v += __shfl_down(v, off, 64);
    return v;
}

// ---------------- kA: A row sums + diag  |  X column sums + p1 = X @ wA1 ----------------
__global__ __launch_bounds__(256) void kA_stats(const float* __restrict__ A,
                                                const float* __restrict__ X,
                                                const float* __restrict__ wA1,
                                                float* __restrict__ rowsum,
                                                float* __restrict__ diagv,
                                                float* __restrict__ p1,
                                                float* __restrict__ colsum_part) {
    if (blockIdx.x < NGRAPH * NNODE / 4) {
        int row  = blockIdx.x * 4 + (threadIdx.x >> 6);
        int lane = threadIdx.x & 63;
        const float4* b4 = (const float4*)(A + (size_t)row * NNODE);
        float sum = 0.f;
        #pragma unroll
        for (int it = 0; it < 4; ++it) {
            float4 v = b4[lane + it * 64];
            sum += v.x + v.y + v.z + v.w;
        }
        sum = wave_reduce(sum);
        if (lane == 0) {
            rowsum[row] = sum;
            int i = row & (NNODE - 1);
            diagv[row] = ((const float*)b4)[i];
        }
    } else {
        int bid  = blockIdx.x - NGRAPH * NNODE / 4;
        int b    = bid >> 3;
        int blk  = bid & 7;
        int wv   = threadIdx.x >> 6;
        int lane = threadIdx.x & 63;
        float w = wA1[lane];
        float cs = 0.f;
        int row0 = blk * 128 + wv * 32;
        const float* Xb = X + (size_t)b * NNODE * DDIM;
        for (int rI = 0; rI < 32; ++rI) {
            int i = row0 + rI;
            float x = Xb[i * DDIM + lane];
            cs += x;
            float v = wave_reduce(x * w);
            if (lane == 0) p1[b * NNODE + i] = v;
        }
        __shared__ float csl[4][64];
        csl[wv][lane] = cs;
        __syncthreads();
        if (threadIdx.x < 64) {
            float t = csl[0][lane] + csl[1][lane] + csl[2][lane] + csl[3][lane];
            colsum_part[(b * 8 + blk) * 64 + lane] = t;
        }
    }
}

// ---------------- kB: per-graph stats + per-node transforms ----------------
// R6 change: x2t written in [b][kt][e][128] layout (k-blocked) so kC's B
// staging loads are fully contiguous 1KB instructions.
__global__ __launch_bounds__(256) void kB_nodes(const float* __restrict__ X,
                                                const float* __restrict__ coeffs,
                                                const float* __restrict__ wA2,
                                                const float* __restrict__ w11,
                                                const float* __restrict__ w12,
                                                const float* __restrict__ w13,
                                                const float* __restrict__ w14,
                                                const float* __restrict__ w15,
                                                const float* __restrict__ w16,
                                                const float* __restrict__ w21,
                                                const float* __restrict__ w22,
                                                const float* __restrict__ w23,
                                                const float* __restrict__ w24,
                                                const float* __restrict__ w25,
                                                const float* __restrict__ w26,
                                                const float* __restrict__ rowsum,
                                                const float* __restrict__ diagv,
                                                const float* __restrict__ colsum_part,
                                                const float* __restrict__ p1g,
                                                float* __restrict__ rws,
                                                float* __restrict__ base0,
                                                unsigned short* __restrict__ x2tg,
                                                float* __restrict__ S2part,
                                                float* __restrict__ R2part,
                                                float* __restrict__ sArr) {
    __shared__ float Xl[64][68];
    __shared__ float w1l[64][68];
    __shared__ float w2l[64][68];
    __shared__ unsigned short X2Tl[64][68];
    __shared__ float rm_l[64], dg_l[64], r_l[64];
    __shared__ float redS[4][64], redR[4][64];
    __shared__ float redA[4], redD[4];
    __shared__ float mxs[64], p2s;
    __shared__ float pg1_l[64], pg2_l[64];

    int b    = blockIdx.x >> 4;
    int tile = blockIdx.x & 15;
    int i0   = tile * 64;
    int tid  = threadIdx.x;
    int e    = tid & 63;
    int wv   = tid >> 6;

    // --- stage X tile + weights ---
    const float* Xg = X + (size_t)b * (NNODE * DDIM) + (size_t)i0 * DDIM;
    #pragma unroll
    for (int it = 0; it < 4; ++it) {
        int g   = it * 256 + tid;
        int row = g >> 4;
        int c4  = (g & 15) << 2;
        float4 v  = ((const float4*)Xg)[g];
        *(float4*)&Xl[row][c4] = v;
        float4 v1 = ((const float4*)w11)[g];
        *(float4*)&w1l[row][c4] = v1;
        float4 v2 = ((const float4*)w21)[g];
        *(float4*)&w2l[row][c4] = v2;
    }

    // --- per-graph scalar stats ---
    float sa = 0.f, sd = 0.f;
    for (int i = tid; i < NNODE; i += 256) {
        sa += rowsum[b * NNODE + i];
        sd += diagv[b * NNODE + i];
    }
    sa = wave_reduce(sa); sd = wave_reduce(sd);
    if (e == 0) { redA[wv] = sa; redD[wv] = sd; }
    if (tid < 64) {
        float mx = 0.f;
        for (int k = 0; k < 8; ++k) mx += colsum_part[(b * 8 + k) * 64 + tid];
        mxs[tid] = mx * (1.f / (float)NNODE);
    }
    __syncthreads();
    float mean_all  = (redA[0] + redA[1] + redA[2] + redA[3]) * (1.f / ((float)NNODE * (float)NNODE));
    float mean_diag = (redD[0] + redD[1] + redD[2] + redD[3]) * (1.f / (float)NNODE);
    float c3 = coeffs[3], c4c = coeffs[4];

    // --- per-graph vectors: one wave per section ---
    if (wv == 0) {
        float a1 = 0.f;
        for (int d = 0; d < 64; ++d) a1 += mxs[d] * w12[e * 64 + d];
        pg1_l[e] = a1 + mean_diag * w15[e] + mean_all * w16[e];
    } else if (wv == 1) {
        float a2 = 0.f;
        for (int d = 0; d < 64; ++d) a2 += mxs[d] * w22[e * 64 + d];
        pg2_l[e] = a2 + mean_diag * w25[e] + mean_all * w26[e];
    } else if (wv == 2) {
        float v = wave_reduce(mxs[e] * wA2[e]);
        if (e == 0) p2s = v;
    } else {
        float rs  = rowsum[b * NNODE + i0 + e];
        float dgv = diagv[b * NNODE + i0 + e];
        float rmv = rs * (1.f / (float)NNODE);
        rm_l[e] = rmv;
        dg_l[e] = dgv;
        float rv = c3 * rmv + c4c * dgv + p1g[b * NNODE + i0 + e];
        r_l[e] = rv;
        rws[b * NNODE + i0 + e] = rv;
    }
    __syncthreads();
    if (tile == 0 && tid == 0)
        sArr[b] = coeffs[1] * mean_all + coeffs[2] * mean_diag + p2s;

    float w13e = w13[e], w14e = w14[e], w23e = w23[e], w24e = w24[e];
    float pg1e = pg1_l[e], pg2e = pg2_l[e];

    float acc1[16], acc2[16];
    #pragma unroll
    for (int t = 0; t < 16; ++t) { acc1[t] = 0.f; acc2[t] = 0.f; }

    for (int d0 = 0; d0 < 64; d0 += 4) {
        float4 w1v = *(const float4*)&w1l[e][d0];
        float4 w2v = *(const float4*)&w2l[e][d0];
        #pragma unroll
        for (int t = 0; t < 16; ++t) {
            int li = wv + 4 * t;
            float4 xv = *(const float4*)&Xl[li][d0];
            acc1[t] += xv.x * w1v.x + xv.y * w1v.y + xv.z * w1v.z + xv.w * w1v.w;
            acc2[t] += xv.x * w2v.x + xv.y * w2v.y + xv.z * w2v.z + xv.w * w2v.w;
        }
    }

    float s2acc = 0.f, r2acc = 0.f;
    #pragma unroll
    for (int t = 0; t < 16; ++t) {
        int li = wv + 4 * t;
        int i  = i0 + li;
        float rmv = rm_l[li], dgv = dg_l[li];
        float x2t = acc2[t] + rmv * w23e + dgv * w24e + pg2e;
        float b0  = acc1[t] + rmv * w13e + dgv * w14e + pg1e;
        base0[((size_t)(b * NNODE + i)) * 64 + e] = b0;
        X2Tl[e][li] = f2bf(x2t);
        s2acc += x2t;
        r2acc += r_l[li] * x2t;
    }
    redS[wv][e] = s2acc;
    redR[wv][e] = r2acc;
    __syncthreads();

    // write X2T in [b][kt][ep][128] layout: node k = i0+e -> kt = tile>>1, k' = (tile&1)*64 + e
    int ktb = tile >> 1;
    int kof = (tile & 1) << 6;
    for (int k = 0; k < 16; ++k) {
        int ep = wv * 16 + k;
        unsigned short v = X2Tl[ep][e];
        x2tg[(((size_t)(b * 8 + ktb) * 64 + ep) << 7) + kof + e] = v;
    }
    if (tid < 64) {
        float s2 = redS[0][tid] + redS[1][tid] + redS[2][tid] + redS[3][tid];
        float r2 = redR[0][tid] + redR[1][tid] + redR[2][tid] + redR[3][tid];
        S2part[(b * 16 + tile) * 64 + tid] = s2;
        R2part[(b * 16 + tile) * 64 + tid] = r2;
    }
}

// ---------------- kC: fused A_t + bf16 MFMA c0*(A @ X2t) + epilogue ----------------
// R6 (resubmitted; round-6 failure matched round-4's infra-flake signature and
// a full audit found no kernel-side failure mechanism).
// WAVE-CONTIGUOUS memory instructions (round-5 diagnosis: 16x 64B-segment
// scatter per instruction -> transaction/DRAM-stride bound at 2.6 TB/s).
//  - Block = 16-row tile, 4 waves (wave s owns output e-slice s and A rows 4s..4s+3).
//  - A loads: 2x 1KB-contiguous instr/wave/kt (lane l -> row +`l>>5`, col (l&31)*4).
//  - At computed from those regs, stored with the same contiguous mapping.
//  - A repacked bf16 into double-buffered LDS tile with XOR swizzle ^((row&7)<<4)
//    (write+read both swizzled -> bank-uniform b64 writes / b128 frag reads).
//  - B staged from k-blocked x2t ([b][kt][e][128]) as 4x fully-contiguous 1KB
//    loads into wave-private double-buffered LDS (same swizzle).
//  - One lgkm-only barrier per kt (A tile is cross-wave); At stores and global
//    prefetches stay in flight across it (no vmcnt drain).
//  - Double buffering race-free: frag reads(kt) precede stage-writes(kt+1) in
//    each iter, barrier separates writes(kt+1) from reads(kt+1).
__global__ __launch_bounds__(256, 3) void kC_main(const float* __restrict__ A,
                                               const float* __restrict__ coeffs,
                                               const float* __restrict__ sArr,
                                               const float* __restrict__ rArr,
                                               const unsigned short* __restrict__ x2tg,
                                               const float* __restrict__ base0,
                                               const float* __restrict__ S2part,
                                               const float* __restrict__ R2part,
                                               float* __restrict__ At,
                                               float* __restrict__ outp) {
    __shared__ float r_lds[1024];
    __shared__ float s2_lds[64], r2_lds[64];
    __shared__ float redS[4][64], redR[4][64];
    __shared__ __align__(16) unsigned char AL[2][4096];      // A-tile bf16 [16][128], swizzled
    __shared__ __align__(16) unsigned char BL[4][2][4096];   // per-wave B [16][128] bf16, swizzled

    int b    = blockIdx.x >> 6;      // 64 blocks per graph
    int tile = blockIdx.x & 63;
    int i0   = tile * 16;
    int tid  = threadIdx.x;
    int l    = tid & 63, s = tid >> 6;
    int m    = l & 15, q = l >> 4;

    // ---- stage r (contiguous) + parallel S2/R2 partial reduce ----
    float4 rv = ((const float4*)(rArr + b * NNODE))[tid];
    *(float4*)&r_lds[tid * 4] = rv;
    {
        float s2p = 0.f, r2p = 0.f;
        #pragma unroll
        for (int t2 = 0; t2 < 4; ++t2) {
            int t = s * 4 + t2;
            s2p += S2part[(b * 16 + t) * 64 + l];
            r2p += R2part[(b * 16 + t) * 64 + l];
        }
        redS[s][l] = s2p;
        redR[s][l] = r2p;
    }

    float sb  = sArr[b];
    float c0  = coeffs[0];
    float c0n = c0 * (1.f / (float)NNODE);

    // ---- per-lane global pointers (contiguous mappings) ----
    int rl0 = 4 * s + (l >> 5);          // j=0 local row
    int rl1 = rl0 + 2;                   // j=1 local row
    const float* A0  = A  + ((size_t)(b * NNODE + i0 + rl0)) * NNODE + (l & 31) * 4;
    const float* A1  = A0 + 2 * (size_t)NNODE;
    float*       At0 = At + ((size_t)(b * NNODE + i0 + rl0)) * NNODE + (l & 31) * 4;
    float*       At1 = At0 + 2 * (size_t)NNODE;
    const unsigned short* Bg = x2tg + (((size_t)(b * 8) * 64) + 16 * s) * 128 + l * 8;
    // per-kt B stride = 64*128 = 8192 ushorts

    // ---- LDS offsets (XOR-swizzled) ----
    unsigned awo0 = rl0 * 256 + (((l & 31) * 8) ^ ((rl0 & 7) << 4));
    unsigned awo1 = rl1 * 256 + (((l & 31) * 8) ^ ((rl1 & 7) << 4));
    unsigned bwo[4];
    #pragma unroll
    for (int c = 0; c < 4; ++c) {
        int rp = 4 * c + (l >> 4);
        bwo[c] = rp * 256 + (((l & 15) * 16) ^ ((rp & 7) << 4));
    }
    unsigned fro[4];
    #pragma unroll
    for (int ks = 0; ks < 4; ++ks)
        fro[ks] = m * 256 + ((ks * 64 + q * 16) ^ ((m & 7) << 4));

    // ---- prologue: issue kt=0 loads (no LDS dependency) ----
    f32x4 a0 = *(const f32x4*)(A0);
    f32x4 a1 = *(const f32x4*)(A1);
    bf16x8 bb0 = *(const bf16x8*)(Bg);
    bf16x8 bb1 = *(const bf16x8*)(Bg + 512);
    bf16x8 bb2 = *(const bf16x8*)(Bg + 1024);
    bf16x8 bb3 = *(const bf16x8*)(Bg + 1536);

    __syncthreads();   // r_lds / redS ready
    if (tid < 64) {
        s2_lds[tid] = (redS[0][tid] + redS[1][tid] + redS[2][tid] + redS[3][tid]) * (1.f / (float)NNODE);
        r2_lds[tid] = (redR[0][tid] + redR[1][tid] + redR[2][tid] + redR[3][tid]) * (1.f / (float)NNODE);
    }
    float bse0 = sb + r_lds[i0 + rl0];
    float bse1 = sb + r_lds[i0 + rl1];

    // ---- stage kt=0: At compute/store + bf16 pack into LDS buf 0 ----
    {
        f32x4 rj = *(const f32x4*)&r_lds[(l & 31) * 4];
        f32x4 t0, t1;
        t0.x = fmaf(c0, a0.x, bse0 + rj.x);
        t0.y = fmaf(c0, a0.y, bse0 + rj.y);
        t0.z = fmaf(c0, a0.z, bse0 + rj.z);
        t0.w = fmaf(c0, a0.w, bse0 + rj.w);
        t1.x = fmaf(c0, a1.x, bse1 + rj.x);
        t1.y = fmaf(c0, a1.y, bse1 + rj.y);
        t1.z = fmaf(c0, a1.z, bse1 + rj.z);
        t1.w = fmaf(c0, a1.w, bse1 + rj.w);
        *(f32x4*)(At0) = t0;
        *(f32x4*)(At1) = t1;
        uint2 w0, w1;
        w0.x = cvt_pk_bf16(a0.x, a0.y); w0.y = cvt_pk_bf16(a0.z, a0.w);
        w1.x = cvt_pk_bf16(a1.x, a1.y); w1.y = cvt_pk_bf16(a1.z, a1.w);
        *(uint2*)(&AL[0][0] + awo0) = w0;
        *(uint2*)(&AL[0][0] + awo1) = w1;
        *(bf16x8*)(&BL[s][0][0] + bwo[0]) = bb0;
        *(bf16x8*)(&BL[s][0][0] + bwo[1]) = bb1;
        *(bf16x8*)(&BL[s][0][0] + bwo[2]) = bb2;
        *(bf16x8*)(&BL[s][0][0] + bwo[3]) = bb3;
    }
    asm volatile("s_waitcnt lgkmcnt(0)\n\ts_barrier" ::: "memory");

    f32x4 acc = {0.f, 0.f, 0.f, 0.f};

    #pragma unroll
    for (int kt = 0; kt < 8; ++kt) {
        const int buf = kt & 1, nbuf = buf ^ 1;

        // ---- prefetch kt+1 (contiguous; lands under the MFMA phase) ----
        if (kt < 7) {
            a0 = *(const f32x4*)(A0 + (kt + 1) * 128);
            a1 = *(const f32x4*)(A1 + (kt + 1) * 128);
            bb0 = *(const bf16x8*)(Bg + (size_t)(kt + 1) * 8192);
            bb1 = *(const bf16x8*)(Bg + (size_t)(kt + 1) * 8192 + 512);
            bb2 = *(const bf16x8*)(Bg + (size_t)(kt + 1) * 8192 + 1024);
            bb3 = *(const bf16x8*)(Bg + (size_t)(kt + 1) * 8192 + 1536);
        }

        // ---- fragments from LDS + 4 MFMAs ----
        {
            bf16x8 af0 = *(const bf16x8*)(&AL[buf][0] + fro[0]);
            bf16x8 bf0 = *(const bf16x8*)(&BL[s][buf][0] + fro[0]);
            bf16x8 af1 = *(const bf16x8*)(&AL[buf][0] + fro[1]);
            bf16x8 bf1 = *(const bf16x8*)(&BL[s][buf][0] + fro[1]);
            bf16x8 af2 = *(const bf16x8*)(&AL[buf][0] + fro[2]);
            bf16x8 bf2 = *(const bf16x8*)(&BL[s][buf][0] + fro[2]);
            bf16x8 af3 = *(const bf16x8*)(&AL[buf][0] + fro[3]);
            bf16x8 bf3 = *(const bf16x8*)(&BL[s][buf][0] + fro[3]);
            acc = __builtin_amdgcn_mfma_f32_16x16x32_bf16(af0, bf0, acc, 0, 0, 0);
            acc = __builtin_amdgcn_mfma_f32_16x16x32_bf16(af1, bf1, acc, 0, 0, 0);
            acc = __builtin_amdgcn_mfma_f32_16x16x32_bf16(af2, bf2, acc, 0, 0, 0);
            acc = __builtin_amdgcn_mfma_f32_16x16x32_bf16(af3, bf3, acc, 0, 0, 0);
        }

        // ---- stage kt+1 into nbuf (after this iter's frag reads) ----
        if (kt < 7) {
            f32x4 rj = *(const f32x4*)&r_lds[(kt + 1) * 128 + (l & 31) * 4];
            f32x4 t0, t1;
            t0.x = fmaf(c0, a0.x, bse0 + rj.x);
            t0.y = fmaf(c0, a0.y, bse0 + rj.y);
            t0.z = fmaf(c0, a0.z, bse0 + rj.z);
            t0.w = fmaf(c0, a0.w, bse0 + rj.w);
            t1.x = fmaf(c0, a1.x, bse1 + rj.x);
            t1.y = fmaf(c0, a1.y, bse1 + rj.y);
            t1.z = fmaf(c0, a1.z, bse1 + rj.z);
            t1.w = fmaf(c0, a1.w, bse1 + rj.w);
            *(f32x4*)(At0 + (kt + 1) * 128) = t0;
            *(f32x4*)(At1 + (kt + 1) * 128) = t1;
            uint2 w0, w1;
            w0.x = cvt_pk_bf16(a0.x, a0.y); w0.y = cvt_pk_bf16(a0.z, a0.w);
            w1.x = cvt_pk_bf16(a1.x, a1.y); w1.y = cvt_pk_bf16(a1.z, a1.w);
            *(uint2*)(&AL[nbuf][0] + awo0) = w0;
            *(uint2*)(&AL[nbuf][0] + awo1) = w1;
            *(bf16x8*)(&BL[s][nbuf][0] + bwo[0]) = bb0;
            *(bf16x8*)(&BL[s][nbuf][0] + bwo[1]) = bb1;
            *(bf16x8*)(&BL[s][nbuf][0] + bwo[2]) = bb2;
            *(bf16x8*)(&BL[s][nbuf][0] + bwo[3]) = bb3;
            asm volatile("s_waitcnt lgkmcnt(0)\n\ts_barrier" ::: "memory");
        }
    }

    // ---- epilogue: out = c0/n * (A@X2t) + base0 + (s + r_i)*S2/n + R2/n ----
    float s2 = s2_lds[16 * s + m];
    float r2 = r2_lds[16 * s + m];
    #pragma unroll
    for (int reg = 0; reg < 4; ++reg) {
        int i = i0 + q * 4 + reg;
        float v = acc[reg] * c0n
                + base0[((size_t)(b * NNODE + i)) * 64 + 16 * s + m]
                + (sb + r_lds[i]) * s2 + r2;
        outp[((size_t)(b * NNODE + i)) * 64 + 16 * s + m] = v;
    }
}

extern "C" void kernel_launch(void* const* d_in, const int* in_sizes, int n_in,
                              void* d_out, int out_size, void* d_ws, size_t ws_size,
                              hipStream_t stream) {
    const float* A      = (const float*)d_in[0];
    const float* X      = (const float*)d_in[1];
    const float* coeffs = (const float*)d_in[2];
    const float* wA1    = (const float*)d_in[3];
    const float* wA2    = (const float*)d_in[4];
    const float* w11    = (const float*)d_in[5];
    const float* w12    = (const float*)d_in[6];
    const float* w13    = (const float*)d_in[7];
    const float* w14    = (const float*)d_in[8];
    const float* w15    = (const float*)d_in[9];
    const float* w16    = (const float*)d_in[10];
    const float* w21    = (const float*)d_in[11];
    const float* w22    = (const float*)d_in[12];
    const float* w23    = (const float*)d_in[13];
    const float* w24    = (const float*)d_in[14];
    const float* w25    = (const float*)d_in[15];
    const float* w26    = (const float*)d_in[16];

    float* ws  = (float*)d_ws;
    float* At  = (float*)d_out;
    float* out = (float*)d_out + (size_t)NGRAPH * NNODE * NNODE;

    float* rowsum = ws + OFF_ROWSUM;
    float* diagv  = ws + OFF_DIAG;
    float* p1     = ws + OFF_P1;
    float* rws    = ws + OFF_R;
    float* cspart = ws + OFF_CS;
    float* sArr   = ws + OFF_S;
    float* S2part = ws + OFF_S2P;
    float* R2part = ws + OFF_R2P;
    float* base0  = ws + OFF_BASE0;
    unsigned short* x2tg = (unsigned short*)(ws + OFF_X2T);

    kA_stats<<<NGRAPH * NNODE / 4 + NGRAPH * 8, 256, 0, stream>>>(
        A, X, wA1, rowsum, diagv, p1, cspart);
    kB_nodes<<<NGRAPH * 16, 256, 0, stream>>>(
        X, coeffs, wA2, w11, w12, w13, w14, w15, w16,
        w21, w22, w23, w24, w25, w26,
        rowsum, diagv, cspart, p1,
        rws, base0, x2tg, S2part, R2part, sArr);
    kC_main<<<NGRAPH * 64, 256, 0, stream>>>(
        A, coeffs, sArr, rws, x2tg, base0, S2part, R2part, At, out);
}

// Round 8
// 197.151 us; speedup vs baseline: 1.0670x; 1.0035x over previous
//
#include <hip/hip_runtime.h>
#include <hip/hip_bf16.h>

#define NGRAPH 16
#define NNODE 1024
#define DDIM 64

typedef __attribute__((ext_vector_type(8))) short bf16x8;
typedef __attribute__((ext_vector_type(4))) float f32x4;

// ---- workspace layout (float offsets) ----
#define OFF_ROWSUM 0            // 16384
#define OFF_DIAG   16384        // 16384
#define OFF_P1     32768        // 16384
#define OFF_R      49152        // 16384
#define OFF_CS     65536        // 16*8*64 = 8192
#define OFF_S      73728        // 16 (+ pad)
#define OFF_S2P    75840        // 16384
#define OFF_R2P    92224        // 16384
#define OFF_BASE0  110656       // 16*1024*64 = 1048576
#define OFF_X2T    1159232      // ushort area: 16*8*64*128 ushorts = 524288 floats

__device__ __forceinline__ unsigned short f2bf(float f) {
    unsigned int u = __float_as_uint(f);
    u = (u + 0x7fffu + ((u >> 16) & 1u)) >> 16;
    return (unsigned short)u;
}

// single-instruction packed f32->bf16 (RNE, same rounding as f2bf)
__device__ __forceinline__ unsigned int cvt_pk_bf16(float lo, float hi) {
    unsigned int r;
    asm("v_cvt_pk_bf16_f32 %0, %1, %2" : "=v"(r) : "v"(lo), "v"(hi));
    return r;
}

__device__ __forceinline__ float wave_reduce(float v) {
    #pragma unroll
    for (int off = 32; off; off >>= 1) v += __shfl_down(v, off, 64);
    return v;
}

// ---------------- kA: A row sums + diag  |  X column sums + p1 = X @ wA1 ----------------
__global__ __launch_bounds__(256) void kA_stats(const float* __restrict__ A,
                                                const float* __restrict__ X,
                                                const float* __restrict__ wA1,
                                                float* __restrict__ rowsum,
                                                float* __restrict__ diagv,
                                                float* __restrict__ p1,
                                                float* __restrict__ colsum_part) {
    if (blockIdx.x < NGRAPH * NNODE / 4) {
        int row  = blockIdx.x * 4 + (threadIdx.x >> 6);
        int lane = threadIdx.x & 63;
        const float4* b4 = (const float4*)(A + (size_t)row * NNODE);
        float sum = 0.f;
        #pragma unroll
        for (int it = 0; it < 4; ++it) {
            float4 v = b4[lane + it * 64];
            sum += v.x + v.y + v.z + v.w;
        }
        sum = wave_reduce(sum);
        if (lane == 0) {
            rowsum[row] = sum;
            int i = row & (NNODE - 1);
            diagv[row] = ((const float*)b4)[i];
        }
    } else {
        int bid  = blockIdx.x - NGRAPH * NNODE / 4;
        int b    = bid >> 3;
        int blk  = bid & 7;
        int wv   = threadIdx.x >> 6;
        int lane = threadIdx.x & 63;
        float w = wA1[lane];
        float cs = 0.f;
        int row0 = blk * 128 + wv * 32;
        const float* Xb = X + (size_t)b * NNODE * DDIM;
        for (int rI = 0; rI < 32; ++rI) {
            int i = row0 + rI;
            float x = Xb[i * DDIM + lane];
            cs += x;
            float v = wave_reduce(x * w);
            if (lane == 0) p1[b * NNODE + i] = v;
        }
        __shared__ float csl[4][64];
        csl[wv][lane] = cs;
        __syncthreads();
        if (threadIdx.x < 64) {
            float t = csl[0][lane] + csl[1][lane] + csl[2][lane] + csl[3][lane];
            colsum_part[(b * 8 + blk) * 64 + lane] = t;
        }
    }
}

// ---------------- kB: per-graph stats + per-node transforms ----------------
// x2t written in [b][kt][e][128] layout (k-blocked) so kC's B staging loads
// are fully contiguous 1KB instructions.
__global__ __launch_bounds__(256) void kB_nodes(const float* __restrict__ X,
                                                const float* __restrict__ coeffs,
                                                const float* __restrict__ wA2,
                                                const float* __restrict__ w11,
                                                const float* __restrict__ w12,
                                                const float* __restrict__ w13,
                                                const float* __restrict__ w14,
                                                const float* __restrict__ w15,
                                                const float* __restrict__ w16,
                                                const float* __restrict__ w21,
                                                const float* __restrict__ w22,
                                                const float* __restrict__ w23,
                                                const float* __restrict__ w24,
                                                const float* __restrict__ w25,
                                                const float* __restrict__ w26,
                                                const float* __restrict__ rowsum,
                                                const float* __restrict__ diagv,
                                                const float* __restrict__ colsum_part,
                                                const float* __restrict__ p1g,
                                                float* __restrict__ rws,
                                                float* __restrict__ base0,
                                                unsigned short* __restrict__ x2tg,
                                                float* __restrict__ S2part,
                                                float* __restrict__ R2part,
                                                float* __restrict__ sArr) {
    __shared__ float Xl[64][68];
    __shared__ float w1l[64][68];
    __shared__ float w2l[64][68];
    __shared__ unsigned short X2Tl[64][68];
    __shared__ float rm_l[64], dg_l[64], r_l[64];
    __shared__ float redS[4][64], redR[4][64];
    __shared__ float redA[4], redD[4];
    __shared__ float mxs[64], p2s;
    __shared__ float pg1_l[64], pg2_l[64];

    int b    = blockIdx.x >> 4;
    int tile = blockIdx.x & 15;
    int i0   = tile * 64;
    int tid  = threadIdx.x;
    int e    = tid & 63;
    int wv   = tid >> 6;

    // --- stage X tile + weights ---
    const float* Xg = X + (size_t)b * (NNODE * DDIM) + (size_t)i0 * DDIM;
    #pragma unroll
    for (int it = 0; it < 4; ++it) {
        int g   = it * 256 + tid;
        int row = g >> 4;
        int c4  = (g & 15) << 2;
        float4 v  = ((const float4*)Xg)[g];
        *(float4*)&Xl[row][c4] = v;
        float4 v1 = ((const float4*)w11)[g];
        *(float4*)&w1l[row][c4] = v1;
        float4 v2 = ((const float4*)w21)[g];
        *(float4*)&w2l[row][c4] = v2;
    }

    // --- per-graph scalar stats ---
    float sa = 0.f, sd = 0.f;
    for (int i = tid; i < NNODE; i += 256) {
        sa += rowsum[b * NNODE + i];
        sd += diagv[b * NNODE + i];
    }
    sa = wave_reduce(sa); sd = wave_reduce(sd);
    if (e == 0) { redA[wv] = sa; redD[wv] = sd; }
    if (tid < 64) {
        float mx = 0.f;
        for (int k = 0; k < 8; ++k) mx += colsum_part[(b * 8 + k) * 64 + tid];
        mxs[tid] = mx * (1.f / (float)NNODE);
    }
    __syncthreads();
    float mean_all  = (redA[0] + redA[1] + redA[2] + redA[3]) * (1.f / ((float)NNODE * (float)NNODE));
    float mean_diag = (redD[0] + redD[1] + redD[2] + redD[3]) * (1.f / (float)NNODE);
    float c3 = coeffs[3], c4c = coeffs[4];

    // --- per-graph vectors: one wave per section ---
    if (wv == 0) {
        float a1 = 0.f;
        for (int d = 0; d < 64; ++d) a1 += mxs[d] * w12[e * 64 + d];
        pg1_l[e] = a1 + mean_diag * w15[e] + mean_all * w16[e];
    } else if (wv == 1) {
        float a2 = 0.f;
        for (int d = 0; d < 64; ++d) a2 += mxs[d] * w22[e * 64 + d];
        pg2_l[e] = a2 + mean_diag * w25[e] + mean_all * w26[e];
    } else if (wv == 2) {
        float v = wave_reduce(mxs[e] * wA2[e]);
        if (e == 0) p2s = v;
    } else {
        float rs  = rowsum[b * NNODE + i0 + e];
        float dgv = diagv[b * NNODE + i0 + e];
        float rmv = rs * (1.f / (float)NNODE);
        rm_l[e] = rmv;
        dg_l[e] = dgv;
        float rv = c3 * rmv + c4c * dgv + p1g[b * NNODE + i0 + e];
        r_l[e] = rv;
        rws[b * NNODE + i0 + e] = rv;
    }
    __syncthreads();
    if (tile == 0 && tid == 0)
        sArr[b] = coeffs[1] * mean_all + coeffs[2] * mean_diag + p2s;

    float w13e = w13[e], w14e = w14[e], w23e = w23[e], w24e = w24[e];
    float pg1e = pg1_l[e], pg2e = pg2_l[e];

    float acc1[16], acc2[16];
    #pragma unroll
    for (int t = 0; t < 16; ++t) { acc1[t] = 0.f; acc2[t] = 0.f; }

    for (int d0 = 0; d0 < 64; d0 += 4) {
        float4 w1v = *(const float4*)&w1l[e][d0];
        float4 w2v = *(const float4*)&w2l[e][d0];
        #pragma unroll
        for (int t = 0; t < 16; ++t) {
            int li = wv + 4 * t;
            float4 xv = *(const float4*)&Xl[li][d0];
            acc1[t] += xv.x * w1v.x + xv.y * w1v.y + xv.z * w1v.z + xv.w * w1v.w;
            acc2[t] += xv.x * w2v.x + xv.y * w2v.y + xv.z * w2v.z + xv.w * w2v.w;
        }
    }

    float s2acc = 0.f, r2acc = 0.f;
    #pragma unroll
    for (int t = 0; t < 16; ++t) {
        int li = wv + 4 * t;
        int i  = i0 + li;
        float rmv = rm_l[li], dgv = dg_l[li];
        float x2t = acc2[t] + rmv * w23e + dgv * w24e + pg2e;
        float b0  = acc1[t] + rmv * w13e + dgv * w14e + pg1e;
        base0[((size_t)(b * NNODE + i)) * 64 + e] = b0;
        X2Tl[e][li] = f2bf(x2t);
        s2acc += x2t;
        r2acc += r_l[li] * x2t;
    }
    redS[wv][e] = s2acc;
    redR[wv][e] = r2acc;
    __syncthreads();

    // write X2T in [b][kt][ep][128] layout: node k = i0+e -> kt = tile>>1, k' = (tile&1)*64 + e
    int ktb = tile >> 1;
    int kof = (tile & 1) << 6;
    for (int k = 0; k < 16; ++k) {
        int ep = wv * 16 + k;
        unsigned short v = X2Tl[ep][e];
        x2tg[(((size_t)(b * 8 + ktb) * 64 + ep) << 7) + kof + e] = v;
    }
    if (tid < 64) {
        float s2 = redS[0][tid] + redS[1][tid] + redS[2][tid] + redS[3][tid];
        float r2 = redR[0][tid] + redR[1][tid] + redR[2][tid] + redR[3][tid];
        S2part[(b * 16 + tile) * 64 + tid] = s2;
        R2part[(b * 16 + tile) * 64 + tid] = r2;
    }
}

// ---------------- kC: fused A_t + bf16 MFMA c0*(A @ X2t) + epilogue ----------------
// R7: R6 wave-contiguous structure + PREFETCH DEPTH 2 (counted vmcnt).
//  - Two in-flight register sets (setA/setB); iteration kt stages kt+1 from the
//    set issued at iteration kt-2 and issues kt+3 -> DRAM latency (~900cy) is
//    covered by >=2 full iterations instead of ~1 MFMA phase (R6's residual
//    stall). Hand-unrolled so all register-set selection is static (rule #20).
//  - Everything else identical to R6: contiguous A loads/At stores, k-blocked
//    x2t B staging, XOR-swizzled double-buffered LDS, lgkm-only barriers.
__global__ __launch_bounds__(256, 3) void kC_main(const float* __restrict__ A,
                                               const float* __restrict__ coeffs,
                                               const float* __restrict__ sArr,
                                               const float* __restrict__ rArr,
                                               const unsigned short* __restrict__ x2tg,
                                               const float* __restrict__ base0,
                                               const float* __restrict__ S2part,
                                               const float* __restrict__ R2part,
                                               float* __restrict__ At,
                                               float* __restrict__ outp) {
    __shared__ float r_lds[1024];
    __shared__ float s2_lds[64], r2_lds[64];
    __shared__ float redS[4][64], redR[4][64];
    __shared__ __align__(16) unsigned char AL[2][4096];      // A-tile bf16 [16][128], swizzled
    __shared__ __align__(16) unsigned char BL[4][2][4096];   // per-wave B [16][128] bf16, swizzled

    int b    = blockIdx.x >> 6;      // 64 blocks per graph
    int tile = blockIdx.x & 63;
    int i0   = tile * 16;
    int tid  = threadIdx.x;
    int l    = tid & 63, s = tid >> 6;
    int m    = l & 15, q = l >> 4;

    // ---- stage r (contiguous) + parallel S2/R2 partial reduce ----
    float4 rv = ((const float4*)(rArr + b * NNODE))[tid];
    *(float4*)&r_lds[tid * 4] = rv;
    {
        float s2p = 0.f, r2p = 0.f;
        #pragma unroll
        for (int t2 = 0; t2 < 4; ++t2) {
            int t = s * 4 + t2;
            s2p += S2part[(b * 16 + t) * 64 + l];
            r2p += R2part[(b * 16 + t) * 64 + l];
        }
        redS[s][l] = s2p;
        redR[s][l] = r2p;
    }

    float sb  = sArr[b];
    float c0  = coeffs[0];
    float c0n = c0 * (1.f / (float)NNODE);

    // ---- per-lane global pointers (contiguous mappings) ----
    int rl0 = 4 * s + (l >> 5);          // j=0 local row
    int rl1 = rl0 + 2;                   // j=1 local row
    const float* A0  = A  + ((size_t)(b * NNODE + i0 + rl0)) * NNODE + (l & 31) * 4;
    const float* A1  = A0 + 2 * (size_t)NNODE;
    float*       At0 = At + ((size_t)(b * NNODE + i0 + rl0)) * NNODE + (l & 31) * 4;
    float*       At1 = At0 + 2 * (size_t)NNODE;
    const unsigned short* Bg = x2tg + (((size_t)(b * 8) * 64) + 16 * s) * 128 + l * 8;
    // per-kt B stride = 64*128 = 8192 ushorts

    // ---- LDS offsets (XOR-swizzled) ----
    unsigned awo0 = rl0 * 256 + (((l & 31) * 8) ^ ((rl0 & 7) << 4));
    unsigned awo1 = rl1 * 256 + (((l & 31) * 8) ^ ((rl1 & 7) << 4));
    unsigned bwo[4];
    #pragma unroll
    for (int c = 0; c < 4; ++c) {
        int rp = 4 * c + (l >> 4);
        bwo[c] = rp * 256 + (((l & 15) * 16) ^ ((rp & 7) << 4));
    }
    unsigned fro[4];
    #pragma unroll
    for (int ks = 0; ks < 4; ++ks)
        fro[ks] = m * 256 + ((ks * 64 + q * 16) ^ ((m & 7) << 4));

    // ---- dual in-flight register sets ----
    f32x4 aA0, aA1, aB0, aB1;
    bf16x8 bA0, bA1, bA2, bA3, bB0, bB1, bB2, bB3;
    f32x4 acc = {0.f, 0.f, 0.f, 0.f};

#define KC_ISSUE(KT, Ar0, Ar1, Br0, Br1, Br2, Br3) do {                         \
    Ar0 = *(const f32x4*)(A0 + (KT) * 128);                                     \
    Ar1 = *(const f32x4*)(A1 + (KT) * 128);                                     \
    Br0 = *(const bf16x8*)(Bg + (size_t)(KT) * 8192);                           \
    Br1 = *(const bf16x8*)(Bg + (size_t)(KT) * 8192 + 512);                     \
    Br2 = *(const bf16x8*)(Bg + (size_t)(KT) * 8192 + 1024);                    \
    Br3 = *(const bf16x8*)(Bg + (size_t)(KT) * 8192 + 1536);                    \
} while (0)

#define KC_STAGE(KT, NB, Ar0, Ar1, Br0, Br1, Br2, Br3) do {                     \
    f32x4 rj = *(const f32x4*)&r_lds[(KT) * 128 + (l & 31) * 4];                \
    f32x4 t0, t1;                                                               \
    t0.x = fmaf(c0, Ar0.x, bse0 + rj.x);                                        \
    t0.y = fmaf(c0, Ar0.y, bse0 + rj.y);                                        \
    t0.z = fmaf(c0, Ar0.z, bse0 + rj.z);                                        \
    t0.w = fmaf(c0, Ar0.w, bse0 + rj.w);                                        \
    t1.x = fmaf(c0, Ar1.x, bse1 + rj.x);                                        \
    t1.y = fmaf(c0, Ar1.y, bse1 + rj.y);                                        \
    t1.z = fmaf(c0, Ar1.z, bse1 + rj.z);                                        \
    t1.w = fmaf(c0, Ar1.w, bse1 + rj.w);                                        \
    *(f32x4*)(At0 + (KT) * 128) = t0;                                           \
    *(f32x4*)(At1 + (KT) * 128) = t1;                                           \
    uint2 w0, w1;                                                               \
    w0.x = cvt_pk_bf16(Ar0.x, Ar0.y); w0.y = cvt_pk_bf16(Ar0.z, Ar0.w);         \
    w1.x = cvt_pk_bf16(Ar1.x, Ar1.y); w1.y = cvt_pk_bf16(Ar1.z, Ar1.w);         \
    *(uint2*)(&AL[NB][0] + awo0) = w0;                                          \
    *(uint2*)(&AL[NB][0] + awo1) = w1;                                          \
    *(bf16x8*)(&BL[s][NB][0] + bwo[0]) = Br0;                                   \
    *(bf16x8*)(&BL[s][NB][0] + bwo[1]) = Br1;                                   \
    *(bf16x8*)(&BL[s][NB][0] + bwo[2]) = Br2;                                   \
    *(bf16x8*)(&BL[s][NB][0] + bwo[3]) = Br3;                                   \
} while (0)

#define KC_MFMA(BUF) do {                                                       \
    bf16x8 af0 = *(const bf16x8*)(&AL[BUF][0] + fro[0]);                        \
    bf16x8 bf0 = *(const bf16x8*)(&BL[s][BUF][0] + fro[0]);                     \
    bf16x8 af1 = *(const bf16x8*)(&AL[BUF][0] + fro[1]);                        \
    bf16x8 bf1 = *(const bf16x8*)(&BL[s][BUF][0] + fro[1]);                     \
    bf16x8 af2 = *(const bf16x8*)(&AL[BUF][0] + fro[2]);                        \
    bf16x8 bf2 = *(const bf16x8*)(&BL[s][BUF][0] + fro[2]);                     \
    bf16x8 af3 = *(const bf16x8*)(&AL[BUF][0] + fro[3]);                        \
    bf16x8 bf3 = *(const bf16x8*)(&BL[s][BUF][0] + fro[3]);                     \
    acc = __builtin_amdgcn_mfma_f32_16x16x32_bf16(af0, bf0, acc, 0, 0, 0);      \
    acc = __builtin_amdgcn_mfma_f32_16x16x32_bf16(af1, bf1, acc, 0, 0, 0);      \
    acc = __builtin_amdgcn_mfma_f32_16x16x32_bf16(af2, bf2, acc, 0, 0, 0);      \
    acc = __builtin_amdgcn_mfma_f32_16x16x32_bf16(af3, bf3, acc, 0, 0, 0);      \
} while (0)

#define KC_BAR asm volatile("s_waitcnt lgkmcnt(0)\n\ts_barrier" ::: "memory")

    // ---- prologue: issue kt=0 (no LDS dependency) ----
    KC_ISSUE(0, aA0, aA1, bA0, bA1, bA2, bA3);

    __syncthreads();   // r_lds / redS ready
    if (tid < 64) {
        s2_lds[tid] = (redS[0][tid] + redS[1][tid] + redS[2][tid] + redS[3][tid]) * (1.f / (float)NNODE);
        r2_lds[tid] = (redR[0][tid] + redR[1][tid] + redR[2][tid] + redR[3][tid]) * (1.f / (float)NNODE);
    }
    float bse0 = sb + r_lds[i0 + rl0];
    float bse1 = sb + r_lds[i0 + rl1];

    // stage kt=0 into buf0, then fill the pipeline: kt=1 -> setA, kt=2 -> setB
    KC_STAGE(0, 0, aA0, aA1, bA0, bA1, bA2, bA3);
    KC_ISSUE(1, aA0, aA1, bA0, bA1, bA2, bA3);
    KC_ISSUE(2, aB0, aB1, bB0, bB1, bB2, bB3);
    KC_BAR;

    // ---- main pipeline: iter kt = {MFMA(kt); stage(kt+1); issue(kt+3); bar} ----
    KC_MFMA(0); KC_STAGE(1, 1, aA0, aA1, bA0, bA1, bA2, bA3);
                KC_ISSUE(3, aA0, aA1, bA0, bA1, bA2, bA3); KC_BAR;
    KC_MFMA(1); KC_STAGE(2, 0, aB0, aB1, bB0, bB1, bB2, bB3);
                KC_ISSUE(4, aB0, aB1, bB0, bB1, bB2, bB3); KC_BAR;
    KC_MFMA(0); KC_STAGE(3, 1, aA0, aA1, bA0, bA1, bA2, bA3);
                KC_ISSUE(5, aA0, aA1, bA0, bA1, bA2, bA3); KC_BAR;
    KC_MFMA(1); KC_STAGE(4, 0, aB0, aB1, bB0, bB1, bB2, bB3);
                KC_ISSUE(6, aB0, aB1, bB0, bB1, bB2, bB3); KC_BAR;
    KC_MFMA(0); KC_STAGE(5, 1, aA0, aA1, bA0, bA1, bA2, bA3);
                KC_ISSUE(7, aA0, aA1, bA0, bA1, bA2, bA3); KC_BAR;
    KC_MFMA(1); KC_STAGE(6, 0, aB0, aB1, bB0, bB1, bB2, bB3); KC_BAR;
    KC_MFMA(0); KC_STAGE(7, 1, aA0, aA1, bA0, bA1, bA2, bA3); KC_BAR;
    KC_MFMA(1);

#undef KC_ISSUE
#undef KC_STAGE
#undef KC_MFMA
#undef KC_BAR

    // ---- epilogue: out = c0/n * (A@X2t) + base0 + (s + r_i)*S2/n + R2/n ----
    float s2 = s2_lds[16 * s + m];
    float r2 = r2_lds[16 * s + m];
    #pragma unroll
    for (int reg = 0; reg < 4; ++reg) {
        int i = i0 + q * 4 + reg;
        float v = acc[reg] * c0n
                + base0[((size_t)(b * NNODE + i)) * 64 + 16 * s + m]
                + (sb + r_lds[i]) * s2 + r2;
        outp[((size_t)(b * NNODE + i)) * 64 + 16 * s + m] = v;
    }
}

extern "C" void kernel_launch(void* const* d_in, const int* in_sizes, int n_in,
                              void* d_out, int out_size, void* d_ws, size_t ws_size,
                              hipStream_t stream) {
    const float* A      = (const float*)d_in[0];
    const float* X      = (const float*)d_in[1];
    const float* coeffs = (const float*)d_in[2];
    const float* wA1    = (const float*)d_in[3];
    const float* wA2    = (const float*)d_in[4];
    const float* w11    = (const float*)d_in[5];
    const float* w12    = (const float*)d_in[6];
    const float* w13    = (const float*)d_in[7];
    const float* w14    = (const float*)d_in[8];
    const float* w15    = (const float*)d_in[9];
    const float* w16    = (const float*)d_in[10];
    const float* w21    = (const float*)d_in[11];
    const float* w22    = (const float*)d_in[12];
    const float* w23    = (const float*)d_in[13];
    const float* w24    = (const float*)d_in[14];
    const float* w25    = (const float*)d_in[15];
    const float* w26    = (const float*)d_in[16];

    float* ws  = (float*)d_ws;
    float* At  = (float*)d_out;
    float* out = (float*)d_out + (size_t)NGRAPH * NNODE * NNODE;

    float* rowsum = ws + OFF_ROWSUM;
    float* diagv  = ws + OFF_DIAG;
    float* p1     = ws + OFF_P1;
    float* rws    = ws + OFF_R;
    float* cspart = ws + OFF_CS;
    float* sArr   = ws + OFF_S;
    float* S2part = ws + OFF_S2P;
    float* R2part = ws + OFF_R2P;
    float* base0  = ws + OFF_BASE0;
    unsigned short* x2tg = (unsigned short*)(ws + OFF_X2T);

    kA_stats<<<NGRAPH * NNODE / 4 + NGRAPH * 8, 256, 0, stream>>>(
        A, X, wA1, rowsum, diagv, p1, cspart);
    kB_nodes<<<NGRAPH * 16, 256, 0, stream>>>(
        X, coeffs, wA2, w11, w12, w13, w14, w15, w16,
        w21, w22, w23, w24, w25, w26,
        rowsum, diagv, cspart, p1,
        rws, base0, x2tg, S2part, R2part, sArr);
    kC_main<<<NGRAPH * 64, 256, 0, stream>>>(
        A, coeffs, sArr, rws, x2tg, base0, S2part, R2part, At, out);
}